// Round 9
// baseline (348.313 us; speedup 1.0000x reference)
//
#include <hip/hip_runtime.h>
#include <hip/hip_bf16.h>

#define B_TOK 16384
#define TOPK 2
#define NEXP 64
#define HID 512
#define FFN 1024
#define NASSIGN (B_TOK * TOPK)   // 32768
#define CAP (NASSIGN / NEXP)     // 512 assignments per expert (balanced)

typedef unsigned short u16;
typedef __bf16 bf16_t;
typedef bf16_t bf16x8 __attribute__((ext_vector_type(8)));
typedef float f32x4 __attribute__((ext_vector_type(4)));

// native cvt: compiler emits v_cvt_pk_bf16_f32 (RTNE)
__device__ __forceinline__ unsigned pkbf(float a, float b) {
  union { bf16_t h[2]; unsigned u; } v;
  v.h[0] = (bf16_t)a; v.h[1] = (bf16_t)b;
  return v.u;
}
__device__ __forceinline__ u16 f2bf(float f) {
  union { bf16_t h; u16 u; } v; v.h = (bf16_t)f; return v.u;
}
__device__ __forceinline__ float bf2f(unsigned u16v) {
  union { unsigned u; float f; } v; v.u = u16v << 16; return v.f;
}

#define GLOAD_LDS16(g, l)                                                     \
  __builtin_amdgcn_global_load_lds((const __attribute__((address_space(1))) void*)(g), \
                                   (__attribute__((address_space(3))) void*)(l), 16, 0, 0)

// ---------------------------------------------------------------- routing
__global__ void k_route(const int* __restrict__ ids, int* __restrict__ cnt,
                        int* __restrict__ tok_of, int* __restrict__ slot_pos) {
  int n = blockIdx.x * blockDim.x + threadIdx.x;
  if (n >= NASSIGN) return;
  int e = ids[n];
  int r = atomicAdd(&cnt[e], 1);
  int p = e * CAP + r;
  tok_of[p] = n >> 1;
  slot_pos[n] = p;
}

// ------------------------------------------------- gather + fp32->bf16 cast
__global__ void k_gather(const float* __restrict__ hs, const int* __restrict__ tok_of,
                         u16* __restrict__ Xg) {
  int p = blockIdx.x * 4 + (threadIdx.x >> 6);
  int lane = threadIdx.x & 63;
  const float4* src = reinterpret_cast<const float4*>(hs + (size_t)tok_of[p] * HID);
  uint2* dst = reinterpret_cast<uint2*>(Xg + (size_t)p * HID);
#pragma unroll
  for (int i = 0; i < 2; i++) {
    float4 v = src[i * 64 + lane];
    uint2 o;
    o.x = pkbf(v.x, v.y);
    o.y = pkbf(v.z, v.w);
    dst[i * 64 + lane] = o;
  }
}

// ------------------------------------------------------------ grouped GEMM
// C[e*CAP+m][n] = sum_k A[e*CAP+m][k] * W[e][k][n]; W fp32 transposed+cvt to
// bf16 [n][k] LDS tiles in-kernel. 256x256, BK=64, 8 waves (2Mx4N).
// m201 phase order: [mem issue] -> sched_bar -> s_barrier -> lgkm0 ->
// sched_bar -> setprio+16 MFMA. Reads cross barriers (each wave waits only
// its own lgkm); depth-1 prefetch strictly into the OPPOSITE dbuf slot so
// no same-buffer write ever races in-flight reads:
//  ph0: issue L(t+1) x8 dwordx4; read a03(8)+b01(4)      | Q(0,0)
//  ph1: stage A(t+1) h0 (2 DMA); read b23(4)             | Q(0,1)
//  ph2: stage A(t+1) h1 (2 DMA); read a47(8, reuse regs) | Q(1,0)
//  ph3: vmcnt(4) [retires L exactly; 4 ADMA in flight];
//       WRITE_B(t+1) 4x b128                             | Q(1,1)
//  tile end: vmcnt(0) (ADMA long-since landed) + barrier.
// Swizzles (both-sides, rule #21): A chunk c -> c^(row&7); B chunk c ->
// c^S(n), S(n)=(n^(n>>3))&7; identical on write and read.
// Epilogue: per-wave-private LDS repack -> uint4 (16B) stores.
template <int K, int NN, bool SILU>
__global__ __launch_bounds__(512, 2) void k_gemm(const u16* __restrict__ A,
                                                 const float* __restrict__ Wf,
                                                 u16* __restrict__ Cout) {
  constexpr int MT = CAP / 256;        // 2
  constexpr int NT = NN / 256;
  constexpr int NWG = NEXP * MT * NT;  // %8 == 0
  constexpr int Q = NWG / 8;
  constexpr int KT = K / 64;           // 8 or 16
  int wg = (blockIdx.x % 8) * Q + blockIdx.x / 8;  // XCD chunked swizzle
  int e = wg / (MT * NT);
  int rm = wg % (MT * NT);
  int mt = rm / NT, nt = rm % NT;

  const u16* Ab = A + ((size_t)e * CAP + (size_t)mt * 256) * K;

  // LDS: A dbuf 2x32KB at 0; B dbuf 2x32KB at 65536. 128KB.
  __shared__ __align__(16) char smc[131072];

  int t_ = threadIdx.x;
  int lane = t_ & 63, wv = t_ >> 6;
  int wm = wv >> 2, wn = wv & 3;        // 2x4 wave grid; wave out = 128x64
  int l15 = lane & 15, lhi = lane >> 4;

  // ---- A staging (global_load_lds)
  int srow = t_ >> 3;
  int gchunk = (t_ & 7) ^ (srow & 7);
  const u16* gA = Ab + (size_t)srow * K + gchunk * 8;
#define STAGE_HALF_A(tn, j)                                                  \
  do {                                                                       \
    char* d_ = smc + ((tn) & 1) * 32768 + (j) * 16384 + wv * 1024;           \
    const u16* s_ = gA + (size_t)((j) * 128) * K + (tn) * 64;                \
    GLOAD_LDS16(s_, d_);                                                     \
    GLOAD_LDS16(s_ + (size_t)64 * K, d_ + 8192);                             \
  } while (0)

  // ---- B staging (reg-staged transpose+cvt from fp32 W[k][n])
  int kunit = t_ >> 6;                  // 0..7 (== wv)
  int nunit = t_ & 63;                  // 0..63
  const float* gWb = Wf + (size_t)e * K * NN + (size_t)(kunit * 8) * NN +
                     (size_t)nt * 256 + nunit * 4;
  int wbo[4];
#pragma unroll
  for (int i = 0; i < 4; i++) {
    int n = nunit * 4 + i;
    int S = (n ^ (n >> 3)) & 7;
    wbo[i] = 65536 + n * 128 + ((kunit ^ S) << 4);
  }

  f32x4 acc[8][4];
#pragma unroll
  for (int i = 0; i < 8; i++)
#pragma unroll
    for (int j = 0; j < 4; j++) {
      f32x4 z = {0.f, 0.f, 0.f, 0.f};
      acc[i][j] = z;
    }
  bf16x8 a[4][2], b[4][2];

  // ---- fragment read offsets (bytes within a 32KB slot)
  int aof0 = (wm * 128 + l15) * 128 + ((lhi ^ (l15 & 7)) << 4);
  int aof1 = (wm * 128 + l15) * 128 + (((4 + lhi) ^ (l15 & 7)) << 4);
  int boff[4][2];
#pragma unroll
  for (int nf = 0; nf < 4; nf++) {
    int r = wn * 64 + nf * 16 + l15;
    int Sr = (r ^ (r >> 3)) & 7;
    boff[nf][0] = r * 128 + ((lhi ^ Sr) << 4);
    boff[nf][1] = r * 128 + (((4 + lhi) ^ Sr) << 4);
  }

#define LOAD_L(tn)                                                           \
  do {                                                                       \
    const float* g_ = gWb + (size_t)(tn) * 64 * NN;                          \
    L0 = *reinterpret_cast<const float4*>(g_);                               \
    L1 = *reinterpret_cast<const float4*>(g_ + (size_t)1 * NN);              \
    L2 = *reinterpret_cast<const float4*>(g_ + (size_t)2 * NN);              \
    L3 = *reinterpret_cast<const float4*>(g_ + (size_t)3 * NN);              \
    L4 = *reinterpret_cast<const float4*>(g_ + (size_t)4 * NN);              \
    L5 = *reinterpret_cast<const float4*>(g_ + (size_t)5 * NN);              \
    L6 = *reinterpret_cast<const float4*>(g_ + (size_t)6 * NN);              \
    L7 = *reinterpret_cast<const float4*>(g_ + (size_t)7 * NN);              \
  } while (0)

#define WRITE_B(tn)                                                          \
  do {                                                                       \
    char* w_ = smc + ((tn) & 1) * 32768;                                     \
    _Pragma("unroll") for (int i = 0; i < 4; i++) {                          \
      uint4 v;                                                               \
      v.x = pkbf(L0[i], L1[i]); v.y = pkbf(L2[i], L3[i]);                    \
      v.z = pkbf(L4[i], L5[i]); v.w = pkbf(L6[i], L7[i]);                    \
      *reinterpret_cast<uint4*>(w_ + wbo[i]) = v;                            \
    }                                                                        \
  } while (0)

#define SBAR()                                                               \
  do {                                                                       \
    __builtin_amdgcn_sched_barrier(0);                                       \
    __builtin_amdgcn_s_barrier();                                            \
  } while (0)
#define LGKM0()                                                              \
  do {                                                                       \
    asm volatile("s_waitcnt lgkmcnt(0)" ::: "memory");                       \
    __builtin_amdgcn_sched_barrier(0);                                       \
  } while (0)

#define MFMA_QUAD(mh, nh)                                                    \
  do {                                                                       \
    __builtin_amdgcn_s_setprio(1);                                           \
    _Pragma("unroll") for (int mf = 0; mf < 4; mf++)                         \
        _Pragma("unroll") for (int nf = 0; nf < 2; nf++)                     \
            _Pragma("unroll") for (int kk = 0; kk < 2; kk++)                 \
                acc[(mh)*4 + mf][(nh)*2 + nf] = __builtin_amdgcn_mfma_f32_16x16x32_bf16( \
                    a[mf][kk], b[(nh)*2 + nf][kk], acc[(mh)*4 + mf][(nh)*2 + nf], 0, 0, 0); \
    __builtin_amdgcn_s_setprio(0);                                           \
  } while (0)

  float4 L0, L1, L2, L3, L4, L5, L6, L7;

  // ---- prologue: A(0) DMA; L(0) -> B slot 0
  STAGE_HALF_A(0, 0); STAGE_HALF_A(0, 1);
  LOAD_L(0);
  asm volatile("s_waitcnt vmcnt(0)" ::: "memory");
  __builtin_amdgcn_sched_barrier(0);
  WRITE_B(0);
  LGKM0();
  __builtin_amdgcn_s_barrier();

#pragma unroll 2
  for (int t = 0; t < KT; t++) {
    const char* pA = smc + (t & 1) * 32768;
    const char* pB = smc + 65536 + (t & 1) * 32768;

    // ---- ph0: issue L(t+1); read a03 + b01
    if (t + 1 < KT) LOAD_L(t + 1);
#pragma unroll
    for (int mf = 0; mf < 4; mf++) {
      a[mf][0] = *reinterpret_cast<const bf16x8*>(pA + aof0 + mf * 2048);
      a[mf][1] = *reinterpret_cast<const bf16x8*>(pA + aof1 + mf * 2048);
    }
#pragma unroll
    for (int nf = 0; nf < 2; nf++) {
      b[nf][0] = *reinterpret_cast<const bf16x8*>(pB + boff[nf][0]);
      b[nf][1] = *reinterpret_cast<const bf16x8*>(pB + boff[nf][1]);
    }
    SBAR(); LGKM0();
    MFMA_QUAD(0, 0);

    // ---- ph1: stage A(t+1) h0; read b23
    if (t + 1 < KT) STAGE_HALF_A(t + 1, 0);
#pragma unroll
    for (int nf = 0; nf < 2; nf++) {
      b[2 + nf][0] = *reinterpret_cast<const bf16x8*>(pB + boff[2 + nf][0]);
      b[2 + nf][1] = *reinterpret_cast<const bf16x8*>(pB + boff[2 + nf][1]);
    }
    SBAR(); LGKM0();
    MFMA_QUAD(0, 1);

    // ---- ph2: stage A(t+1) h1; read a47 (reuse a[] regs; Q(0,1) consumed a03)
    if (t + 1 < KT) STAGE_HALF_A(t + 1, 1);
#pragma unroll
    for (int mf = 0; mf < 4; mf++) {
      a[mf][0] = *reinterpret_cast<const bf16x8*>(pA + aof0 + (4 + mf) * 2048);
      a[mf][1] = *reinterpret_cast<const bf16x8*>(pA + aof1 + (4 + mf) * 2048);
    }
    SBAR(); LGKM0();
    MFMA_QUAD(1, 0);

    // ---- ph3: retire L (counted); write B(t+1)
    if (t + 1 < KT) {
      asm volatile("s_waitcnt vmcnt(4)" ::: "memory");  // L0..7 retired; 4 ADMA in flight
      __builtin_amdgcn_sched_barrier(0);
      WRITE_B(t + 1);
    }
    SBAR(); LGKM0();
    MFMA_QUAD(1, 1);
    asm volatile("s_waitcnt vmcnt(0)" ::: "memory");  // ADMA landed (long flight)
    SBAR();
  }
#undef STAGE_HALF_A
#undef LOAD_L
#undef WRITE_B
#undef MFMA_QUAD

  // ---- epilogue: per-wave-private LDS repack -> uint4 stores
  // region per wave: 16 rows x 68 f32 (pad 4) = 4352B
  {
    char* reg_ = smc + wv * 4352;
    u16* Cb = Cout + ((size_t)e * CAP + mt * 256 + wm * 128) * NN +
              (size_t)nt * 256 + wn * 64;
    int rr = lane >> 2;            // 0..15
    int cg = (lane & 3) * 16;      // 0,16,32,48
    for (int mf = 0; mf < 8; mf++) {
#pragma unroll
      for (int nf = 0; nf < 4; nf++)
#pragma unroll
        for (int rg = 0; rg < 4; rg++) {
          float v = acc[mf][nf][rg];
          if constexpr (SILU) v = v / (1.0f + __expf(-v));
          *reinterpret_cast<float*>(reg_ + (lhi * 4 + rg) * 272 + (nf * 16 + l15) * 4) = v;
        }
      LGKM0();
      f32x4 q0 = *reinterpret_cast<const f32x4*>(reg_ + rr * 272 + cg * 4);
      f32x4 q1 = *reinterpret_cast<const f32x4*>(reg_ + rr * 272 + cg * 4 + 16);
      f32x4 q2 = *reinterpret_cast<const f32x4*>(reg_ + rr * 272 + cg * 4 + 32);
      f32x4 q3 = *reinterpret_cast<const f32x4*>(reg_ + rr * 272 + cg * 4 + 48);
      LGKM0();  // reads in regs before next iter overwrites region
      uint4 s0, s1;
      s0.x = pkbf(q0[0], q0[1]); s0.y = pkbf(q0[2], q0[3]);
      s0.z = pkbf(q1[0], q1[1]); s0.w = pkbf(q1[2], q1[3]);
      s1.x = pkbf(q2[0], q2[1]); s1.y = pkbf(q2[2], q2[3]);
      s1.z = pkbf(q3[0], q3[1]); s1.w = pkbf(q3[2], q3[3]);
      u16* row = Cb + (size_t)(mf * 16 + rr) * NN + cg;
      *reinterpret_cast<uint4*>(row) = s0;
      *reinterpret_cast<uint4*>(row + 8) = s1;
    }
  }
#undef SBAR
#undef LGKM0
}

// ------------------------------------------- weighted combine (no atomics)
__global__ void k_combine(const u16* __restrict__ yws, const int* __restrict__ slot_pos,
                          const float* __restrict__ w, float* __restrict__ out) {
  int tk = blockIdx.x;
  int t = threadIdx.x;
  int p0 = slot_pos[2 * tk], p1 = slot_pos[2 * tk + 1];
  float w0 = w[2 * tk], w1 = w[2 * tk + 1];
  unsigned ua = reinterpret_cast<const unsigned*>(yws + (size_t)p0 * HID)[t];
  unsigned ub = reinterpret_cast<const unsigned*>(yws + (size_t)p1 * HID)[t];
  float2 o;
  o.x = w0 * bf2f(ua & 0xffffu) + w1 * bf2f(ub & 0xffffu);
  o.y = w0 * bf2f(ua >> 16) + w1 * bf2f(ub >> 16);
  reinterpret_cast<float2*>(out + (size_t)tk * HID)[t] = o;
}

// ---------------------------------------------------------------- launcher
extern "C" void kernel_launch(void* const* d_in, const int* in_sizes, int n_in,
                              void* d_out, int out_size, void* d_ws, size_t ws_size,
                              hipStream_t stream) {
  const float* hs = (const float*)d_in[0];
  const float* wts = (const float*)d_in[1];
  const int* ids = (const int*)d_in[2];
  const float* W1 = (const float*)d_in[3];
  const float* W2 = (const float*)d_in[4];
  float* out = (float*)d_out;

  char* ws = (char*)d_ws;
  size_t o = 0;
  int* cnt = (int*)(ws + o);       o += 1024;
  int* slot_pos = (int*)(ws + o);  o += (size_t)NASSIGN * 4;
  int* tok_of = (int*)(ws + o);    o += (size_t)NASSIGN * 4;
  o = (o + 255) & ~(size_t)255;
  u16* Xg = (u16*)(ws + o);        o += (size_t)NASSIGN * HID * 2;      // 32 MB
  u16* hid = (u16*)(ws + o);       o += (size_t)NASSIGN * FFN * 2;      // 64 MB
  u16* yws = (u16*)(ws + o);       o += (size_t)NASSIGN * HID * 2;      // 32 MB

  hipMemsetAsync(cnt, 0, NEXP * sizeof(int), stream);
  k_route<<<(NASSIGN + 255) / 256, 256, 0, stream>>>(ids, cnt, tok_of, slot_pos);
  k_gather<<<NASSIGN / 4, 256, 0, stream>>>(hs, tok_of, Xg);
  k_gemm<HID, FFN, true><<<NEXP * (CAP / 256) * (FFN / 256), 512, 0, stream>>>(Xg, W1, hid);
  k_gemm<FFN, HID, false><<<NEXP * (CAP / 256) * (HID / 256), 512, 0, stream>>>(hid, W2, yws);
  k_combine<<<B_TOK, 256, 0, stream>>>(yws, slot_pos, wts, out);
}

// Round 10
// 271.658 us; speedup vs baseline: 1.2822x; 1.2822x over previous
//
#include <hip/hip_runtime.h>
#include <hip/hip_bf16.h>

#define B_TOK 16384
#define TOPK 2
#define NEXP 64
#define HID 512
#define FFN 1024
#define NASSIGN (B_TOK * TOPK)   // 32768
#define CAP (NASSIGN / NEXP)     // 512 assignments per expert (balanced)

typedef unsigned short u16;
typedef __bf16 bf16_t;
typedef bf16_t bf16x8 __attribute__((ext_vector_type(8)));
typedef float f32x4 __attribute__((ext_vector_type(4)));

// native cvt: compiler emits v_cvt_pk_bf16_f32 (RTNE)
__device__ __forceinline__ unsigned pkbf(float a, float b) {
  union { bf16_t h[2]; unsigned u; } v;
  v.h[0] = (bf16_t)a; v.h[1] = (bf16_t)b;
  return v.u;
}
__device__ __forceinline__ u16 f2bf(float f) {
  union { bf16_t h; u16 u; } v; v.h = (bf16_t)f; return v.u;
}
__device__ __forceinline__ float bf2f(unsigned u16v) {
  union { unsigned u; float f; } v; v.u = u16v << 16; return v.f;
}

#define GLOAD_LDS16(g, l)                                                     \
  __builtin_amdgcn_global_load_lds((const __attribute__((address_space(1))) void*)(g), \
                                   (__attribute__((address_space(3))) void*)(l), 16, 0, 0)

// ---------------------------------------------------------------- routing
__global__ void k_route(const int* __restrict__ ids, int* __restrict__ cnt,
                        int* __restrict__ tok_of, int* __restrict__ slot_pos) {
  int n = blockIdx.x * blockDim.x + threadIdx.x;
  if (n >= NASSIGN) return;
  int e = ids[n];
  int r = atomicAdd(&cnt[e], 1);
  int p = e * CAP + r;
  tok_of[p] = n >> 1;
  slot_pos[n] = p;
}

// ------------------------------------------------- gather + fp32->bf16 cast
__global__ void k_gather(const float* __restrict__ hs, const int* __restrict__ tok_of,
                         u16* __restrict__ Xg) {
  int p = blockIdx.x * 4 + (threadIdx.x >> 6);
  int lane = threadIdx.x & 63;
  const float4* src = reinterpret_cast<const float4*>(hs + (size_t)tok_of[p] * HID);
  uint2* dst = reinterpret_cast<uint2*>(Xg + (size_t)p * HID);
#pragma unroll
  for (int i = 0; i < 2; i++) {
    float4 v = src[i * 64 + lane];
    uint2 o;
    o.x = pkbf(v.x, v.y);
    o.y = pkbf(v.z, v.w);
    dst[i * 64 + lane] = o;
  }
}

// ------------------------------------------------------------ grouped GEMM
// C[e*CAP+m][n] = sum_k A[e*CAP+m][k] * W[e][k][n]; W fp32 transposed+cvt to
// bf16 LDS tiles in-kernel.  R3-proven structure: 128x128 tile, BK=32,
// 4 waves (2x2), double-buffered A and B, ONE __syncthreads per K-tile,
// compiler-managed waitcnts (in-order vmcnt: waiting L never drains the
// younger A-DMA).  Per tile:
//   issue L(t+1) [8 x float2 fp32 W rows] -> ds_read 8 frags(cur) ->
//   issue A-DMA(t+1) [2 x gload_lds, opposite buf] -> 16 MFMA ->
//   WRITE_B(t+1) [2 x uint4, opposite buf] -> __syncthreads.
// A LDS: [128r][32k] bf16 64B rows, chunk swizzle c^(r&3) (pre-swizzled
// global source, linear DMA dest; rule #21 both-sides).
// B LDS: [128n][32k+pad] bf16 rows of 80B. Pad-80 bank math: 16B slot
// index = (5n + chunk) mod 8; gcd(5,8)=1 so frag reads spread all 8 slots
// (2-way = free); B-writes 4-way on 2 instrs only. No XOR needed.
template <int K, int NN, bool SILU>
__global__ __launch_bounds__(256) void k_gemm(const u16* __restrict__ A,
                                              const float* __restrict__ Wf,
                                              u16* __restrict__ Cout) {
  constexpr int MT = CAP / 128;        // 4
  constexpr int NT = NN / 128;         // 8 (G1) / 4 (G2)
  constexpr int NWG = NEXP * MT * NT;  // %8 == 0
  constexpr int Q = NWG / 8;
  constexpr int KT = K / 32;           // 16 (G1) / 32 (G2)
  int wg = (blockIdx.x % 8) * Q + blockIdx.x / 8;  // XCD chunked swizzle
  int e = wg / (MT * NT);
  int rm = wg % (MT * NT);
  int mt = rm / NT, nt = rm % NT;

  const u16* Ab = A + ((size_t)e * CAP + (size_t)mt * 128) * K;

  // LDS: A dbuf 2x8KB at 0; B dbuf 2x10240B at 16384. 36.9 KB total.
  __shared__ __align__(16) char smc[36864];

  int t_ = threadIdx.x;
  int lane = t_ & 63, wv = t_ >> 6;
  int wm = wv >> 1, wn = wv & 1;        // 2x2 wave grid; wave out = 64x64
  int l15 = lane & 15, lhi = lane >> 4;

  // ---- A staging (global_load_lds): row t_>>2 (0..63/call), chunk t_&3,
  // global chunk = (t_&3) ^ (row&3)
  int srow = t_ >> 2;
  int gchunk = (t_ & 3) ^ (srow & 3);
  const u16* gA = Ab + (size_t)srow * K + gchunk * 8;
#define STAGE_A(tn)                                                          \
  do {                                                                       \
    char* d_ = smc + ((tn) & 1) * 8192 + wv * 1024;                          \
    const u16* s_ = gA + (size_t)(tn) * 32;                                  \
    GLOAD_LDS16(s_, d_);                                                     \
    GLOAD_LDS16(s_ + (size_t)64 * K, d_ + 4096);                             \
  } while (0)

  // ---- B staging (reg-staged transpose+cvt from fp32 W[k][n])
  // thread: kg = t_>>6 (k0 = kg*8, 8 rows), ng = t_&63 (n0 = ng*2, 2 cols)
  int kg = t_ >> 6;                     // == wv
  int ng = t_ & 63;                     // == lane
  const float* gWb = Wf + (size_t)e * K * NN + (size_t)(kg * 8) * NN +
                     (size_t)nt * 128 + ng * 2;
  float2 L0, L1, L2, L3, L4, L5, L6, L7;
#define LOAD_L(tn)                                                           \
  do {                                                                       \
    const float* g_ = gWb + (size_t)(tn) * 32 * NN;                          \
    L0 = *reinterpret_cast<const float2*>(g_);                               \
    L1 = *reinterpret_cast<const float2*>(g_ + (size_t)1 * NN);              \
    L2 = *reinterpret_cast<const float2*>(g_ + (size_t)2 * NN);              \
    L3 = *reinterpret_cast<const float2*>(g_ + (size_t)3 * NN);              \
    L4 = *reinterpret_cast<const float2*>(g_ + (size_t)4 * NN);              \
    L5 = *reinterpret_cast<const float2*>(g_ + (size_t)5 * NN);              \
    L6 = *reinterpret_cast<const float2*>(g_ + (size_t)6 * NN);              \
    L7 = *reinterpret_cast<const float2*>(g_ + (size_t)7 * NN);              \
  } while (0)
  // write col n's chunk kg (k = kg*8..kg*8+7) at n*80 + kg*16
#define WRITE_B(tn)                                                          \
  do {                                                                       \
    char* w_ = smc + 16384 + ((tn) & 1) * 10240 + kg * 16;                   \
    uint4 v0, v1;                                                            \
    v0.x = pkbf(L0.x, L1.x); v0.y = pkbf(L2.x, L3.x);                        \
    v0.z = pkbf(L4.x, L5.x); v0.w = pkbf(L6.x, L7.x);                        \
    v1.x = pkbf(L0.y, L1.y); v1.y = pkbf(L2.y, L3.y);                        \
    v1.z = pkbf(L4.y, L5.y); v1.w = pkbf(L6.y, L7.y);                        \
    *reinterpret_cast<uint4*>(w_ + (ng * 2) * 80) = v0;                      \
    *reinterpret_cast<uint4*>(w_ + (ng * 2 + 1) * 80) = v1;                  \
  } while (0)

  f32x4 acc[4][4];
#pragma unroll
  for (int i = 0; i < 4; i++)
#pragma unroll
    for (int j = 0; j < 4; j++) {
      f32x4 z = {0.f, 0.f, 0.f, 0.f};
      acc[i][j] = z;
    }
  bf16x8 a[4], b[4];

  // ---- fragment read offsets (bytes within a buffer)
  int aof[4], bof[4];
#pragma unroll
  for (int f = 0; f < 4; f++) {
    int ar = wm * 64 + f * 16 + l15;
    aof[f] = ar * 64 + ((lhi ^ (ar & 3)) << 4);
    int br = wn * 64 + f * 16 + l15;
    bof[f] = br * 80 + (lhi << 4);
  }

  // ---- prologue: tile 0
  STAGE_A(0);
  LOAD_L(0);
  WRITE_B(0);      // compiler inserts vmcnt wait for L regs
  __syncthreads(); // drains A-DMA + B ds_writes

  for (int t = 0; t < KT; t++) {
    const char* pA = smc + (t & 1) * 8192;
    const char* pB = smc + 16384 + (t & 1) * 10240;

    if (t + 1 < KT) LOAD_L(t + 1);       // issue early (8 VMEM, oldest)
#pragma unroll
    for (int f = 0; f < 4; f++) {
      a[f] = *reinterpret_cast<const bf16x8*>(pA + aof[f]);
      b[f] = *reinterpret_cast<const bf16x8*>(pB + bof[f]);
    }
    if (t + 1 < KT) STAGE_A(t + 1);      // DMA into opposite buf

#pragma unroll
    for (int mf = 0; mf < 4; mf++)
#pragma unroll
      for (int nf = 0; nf < 4; nf++)
        acc[mf][nf] = __builtin_amdgcn_mfma_f32_16x16x32_bf16(a[mf], b[nf], acc[mf][nf], 0, 0, 0);

    if (t + 1 < KT) WRITE_B(t + 1);      // opposite buf; waits L only (in-order)
    __syncthreads();                     // drain + barrier; next tile ready
  }
#undef STAGE_A
#undef LOAD_L
#undef WRITE_B

  // epilogue: D row = lhi*4+reg, col = l15 (verified C/D layout); bf16 out
#pragma unroll
  for (int mf = 0; mf < 4; mf++) {
#pragma unroll
    for (int nf = 0; nf < 4; nf++) {
#pragma unroll
      for (int rg = 0; rg < 4; rg++) {
        float v = acc[mf][nf][rg];
        int grow = mt * 128 + wm * 64 + mf * 16 + lhi * 4 + rg;
        int gcol = nt * 128 + wn * 64 + nf * 16 + l15;
        size_t off = ((size_t)e * CAP + grow) * NN + gcol;
        if constexpr (SILU) v = v / (1.0f + __expf(-v));  // silu
        Cout[off] = f2bf(v);
      }
    }
  }
}

// ------------------------------------------- weighted combine (no atomics)
__global__ void k_combine(const u16* __restrict__ yws, const int* __restrict__ slot_pos,
                          const float* __restrict__ w, float* __restrict__ out) {
  int tk = blockIdx.x;
  int t = threadIdx.x;
  int p0 = slot_pos[2 * tk], p1 = slot_pos[2 * tk + 1];
  float w0 = w[2 * tk], w1 = w[2 * tk + 1];
  unsigned ua = reinterpret_cast<const unsigned*>(yws + (size_t)p0 * HID)[t];
  unsigned ub = reinterpret_cast<const unsigned*>(yws + (size_t)p1 * HID)[t];
  float2 o;
  o.x = w0 * bf2f(ua & 0xffffu) + w1 * bf2f(ub & 0xffffu);
  o.y = w0 * bf2f(ua >> 16) + w1 * bf2f(ub >> 16);
  reinterpret_cast<float2*>(out + (size_t)tk * HID)[t] = o;
}

// ---------------------------------------------------------------- launcher
extern "C" void kernel_launch(void* const* d_in, const int* in_sizes, int n_in,
                              void* d_out, int out_size, void* d_ws, size_t ws_size,
                              hipStream_t stream) {
  const float* hs = (const float*)d_in[0];
  const float* wts = (const float*)d_in[1];
  const int* ids = (const int*)d_in[2];
  const float* W1 = (const float*)d_in[3];
  const float* W2 = (const float*)d_in[4];
  float* out = (float*)d_out;

  char* ws = (char*)d_ws;
  size_t o = 0;
  int* cnt = (int*)(ws + o);       o += 1024;
  int* slot_pos = (int*)(ws + o);  o += (size_t)NASSIGN * 4;
  int* tok_of = (int*)(ws + o);    o += (size_t)NASSIGN * 4;
  o = (o + 255) & ~(size_t)255;
  u16* Xg = (u16*)(ws + o);        o += (size_t)NASSIGN * HID * 2;      // 32 MB
  u16* hid = (u16*)(ws + o);       o += (size_t)NASSIGN * FFN * 2;      // 64 MB
  u16* yws = (u16*)(ws + o);       o += (size_t)NASSIGN * HID * 2;      // 32 MB

  hipMemsetAsync(cnt, 0, NEXP * sizeof(int), stream);
  k_route<<<(NASSIGN + 255) / 256, 256, 0, stream>>>(ids, cnt, tok_of, slot_pos);
  k_gather<<<NASSIGN / 4, 256, 0, stream>>>(hs, tok_of, Xg);
  k_gemm<HID, FFN, true><<<NEXP * (CAP / 128) * (FFN / 128), 256, 0, stream>>>(Xg, W1, hid);
  k_gemm<FFN, HID, false><<<NEXP * (CAP / 128) * (HID / 128), 256, 0, stream>>>(hid, W2, yws);
  k_combine<<<B_TOK, 256, 0, stream>>>(yws, slot_pos, wts, out);
}

// Round 11
// 256.212 us; speedup vs baseline: 1.3595x; 1.0603x over previous
//
#include <hip/hip_runtime.h>
#include <hip/hip_bf16.h>

#define B_TOK 16384
#define TOPK 2
#define NEXP 64
#define HID 512
#define FFN 1024
#define NASSIGN (B_TOK * TOPK)   // 32768
#define CAP (NASSIGN / NEXP)     // 512 assignments per expert (balanced)

typedef unsigned short u16;
typedef __bf16 bf16_t;
typedef bf16_t bf16x8 __attribute__((ext_vector_type(8)));
typedef float f32x4 __attribute__((ext_vector_type(4)));

// native cvt: compiler emits v_cvt_pk_bf16_f32 (RTNE)
__device__ __forceinline__ unsigned pkbf(float a, float b) {
  union { bf16_t h[2]; unsigned u; } v;
  v.h[0] = (bf16_t)a; v.h[1] = (bf16_t)b;
  return v.u;
}
__device__ __forceinline__ u16 f2bf(float f) {
  union { bf16_t h; u16 u; } v; v.h = (bf16_t)f; return v.u;
}
__device__ __forceinline__ float bf2f(unsigned u16v) {
  union { unsigned u; float f; } v; v.u = u16v << 16; return v.f;
}

#define GLOAD_LDS16(g, l)                                                     \
  __builtin_amdgcn_global_load_lds((const __attribute__((address_space(1))) void*)(g), \
                                   (__attribute__((address_space(3))) void*)(l), 16, 0, 0)

// ---------------------------------------------------------------- routing
__global__ void k_route(const int* __restrict__ ids, int* __restrict__ cnt,
                        int* __restrict__ tok_of, int* __restrict__ slot_pos) {
  int n = blockIdx.x * blockDim.x + threadIdx.x;
  if (n >= NASSIGN) return;
  int e = ids[n];
  int r = atomicAdd(&cnt[e], 1);
  int p = e * CAP + r;
  tok_of[p] = n >> 1;
  slot_pos[n] = p;
}

// ------------------------------------------------- gather + fp32->bf16 cast
__global__ void k_gather(const float* __restrict__ hs, const int* __restrict__ tok_of,
                         u16* __restrict__ Xg) {
  int p = blockIdx.x * 4 + (threadIdx.x >> 6);
  int lane = threadIdx.x & 63;
  const float4* src = reinterpret_cast<const float4*>(hs + (size_t)tok_of[p] * HID);
  uint2* dst = reinterpret_cast<uint2*>(Xg + (size_t)p * HID);
#pragma unroll
  for (int i = 0; i < 2; i++) {
    float4 v = src[i * 64 + lane];
    uint2 o;
    o.x = pkbf(v.x, v.y);
    o.y = pkbf(v.z, v.w);
    dst[i * 64 + lane] = o;
  }
}

// ------------------------------------------------------------ grouped GEMM
// C[e*CAP+m][n] = sum_k A[e*CAP+m][k] * W[e][k][n]; W fp32 transposed+cvt to
// bf16 LDS in-kernel.  R3-proven structure: 128x128 tile, BK=32, 4 waves
// (2x2), dbuf A+B, ONE __syncthreads per K-tile, compiler-managed waits.
// LDS layout (A and B identical): logical (row r, 16B chunk c in 0..3) at
//   byte (r>>1)*128 + ((4*(r&1)+c) ^ ((r>>1)&7))*16
// 3-bit XOR within each 128B pair-window (bijective). Conflict math:
//  - frag reads (16 lanes, consecutive r, c=lhi fixed): slots cycle all 8,
//    2 lanes/slot -> free.
//  - B writes (uint4, instr i: col n=2*lane+i, chunk kg fixed): slot =
//    (4i+kg)^(lane&7) -> all 8 slots uniform -> 0 conflicts (fixes R10).
//  - A staged via global_load_lds with inverse-permuted per-lane SOURCE
//    (rule #21: linear LDS dest; decode phys chunk -> logical (r,c)).
template <int K, int NN, bool SILU>
__global__ __launch_bounds__(256, 4) void k_gemm(const u16* __restrict__ A,
                                                 const float* __restrict__ Wf,
                                                 u16* __restrict__ Cout) {
  constexpr int MT = CAP / 128;        // 4
  constexpr int NT = NN / 128;         // 8 (G1) / 4 (G2)
  constexpr int NWG = NEXP * MT * NT;  // %8 == 0
  constexpr int Qx = NWG / 8;
  constexpr int KT = K / 32;           // 16 / 32
  int wg = (blockIdx.x % 8) * Qx + blockIdx.x / 8;  // XCD chunked swizzle
  int e = wg / (MT * NT);
  int rm = wg % (MT * NT);
  int mt = rm / NT, nt = rm % NT;

  const u16* Ab = A + ((size_t)e * CAP + (size_t)mt * 128) * K;

  // LDS: A dbuf 2x8KB at 0; B dbuf 2x8KB at 16384. 32KB.
  __shared__ __align__(16) char smc[32768];

  int t_ = threadIdx.x;
  int lane = t_ & 63, wv = t_ >> 6;
  int wm = wv >> 1, wn = wv & 1;        // 2x2 wave grid; wave out = 64x64
  int l15 = lane & 15, lhi = lane >> 4;

  // ---- A staging: DMA call j writes phys chunks m = t_ + 256*j linearly.
  // Decode phys m -> logical (r,c):  pair=m>>3, x=(m&7)^(pair&7),
  // r=2*pair+(x>>2), c=x&3.  Source = Ab + r*K + c*8 (+ tile k offset).
  int pr0 = t_ >> 3, x0 = (t_ & 7) ^ (pr0 & 7);
  int m1 = t_ + 256;
  int pr1 = m1 >> 3, x1 = (m1 & 7) ^ (pr1 & 7);
  const u16* gA0 = Ab + (size_t)(2 * pr0 + (x0 >> 2)) * K + (x0 & 3) * 8;
  const u16* gA1 = Ab + (size_t)(2 * pr1 + (x1 >> 2)) * K + (x1 & 3) * 8;
#define STAGE_A(tn)                                                          \
  do {                                                                       \
    char* d_ = smc + ((tn) & 1) * 8192 + wv * 1024;                          \
    GLOAD_LDS16(gA0 + (size_t)(tn) * 32, d_);                                \
    GLOAD_LDS16(gA1 + (size_t)(tn) * 32, d_ + 4096);                         \
  } while (0)

  // ---- B staging: thread owns cols n=2*lane, 2*lane+1; k-chunk kg=wv
  // (k = kg*8 .. kg*8+7).  8 float2 loads (adjacent cols), 2 uint4 writes.
  int kg = wv;
  const float* gWb = Wf + (size_t)e * K * NN + (size_t)(kg * 8) * NN +
                     (size_t)nt * 128 + lane * 2;
  int wb0 = 16384 + lane * 128 + ((4 * 0 + kg) ^ (lane & 7)) * 16;  // col 2*lane
  int wb1 = 16384 + lane * 128 + ((4 * 1 + kg) ^ (lane & 7)) * 16;  // col 2*lane+1
  float2 L0, L1, L2, L3, L4, L5, L6, L7;
#define LOAD_L(tn)                                                           \
  do {                                                                       \
    const float* g_ = gWb + (size_t)(tn) * 32 * NN;                          \
    L0 = *reinterpret_cast<const float2*>(g_);                               \
    L1 = *reinterpret_cast<const float2*>(g_ + (size_t)1 * NN);              \
    L2 = *reinterpret_cast<const float2*>(g_ + (size_t)2 * NN);              \
    L3 = *reinterpret_cast<const float2*>(g_ + (size_t)3 * NN);              \
    L4 = *reinterpret_cast<const float2*>(g_ + (size_t)4 * NN);              \
    L5 = *reinterpret_cast<const float2*>(g_ + (size_t)5 * NN);              \
    L6 = *reinterpret_cast<const float2*>(g_ + (size_t)6 * NN);              \
    L7 = *reinterpret_cast<const float2*>(g_ + (size_t)7 * NN);              \
  } while (0)
#define WRITE_B(tn)                                                          \
  do {                                                                       \
    char* w_ = smc + ((tn) & 1) * 8192;                                      \
    uint4 v0, v1;                                                            \
    v0.x = pkbf(L0.x, L1.x); v0.y = pkbf(L2.x, L3.x);                        \
    v0.z = pkbf(L4.x, L5.x); v0.w = pkbf(L6.x, L7.x);                        \
    v1.x = pkbf(L0.y, L1.y); v1.y = pkbf(L2.y, L3.y);                        \
    v1.z = pkbf(L4.y, L5.y); v1.w = pkbf(L6.y, L7.y);                        \
    *reinterpret_cast<uint4*>(w_ + wb0) = v0;                                \
    *reinterpret_cast<uint4*>(w_ + wb1) = v1;                                \
  } while (0)

  f32x4 acc[4][4];
#pragma unroll
  for (int i = 0; i < 4; i++)
#pragma unroll
    for (int j = 0; j < 4; j++) {
      f32x4 z = {0.f, 0.f, 0.f, 0.f};
      acc[i][j] = z;
    }
  bf16x8 a[4], b[4];

  // ---- fragment read offsets (swizzled layout)
  int aof[4], bof[4];
#pragma unroll
  for (int f = 0; f < 4; f++) {
    int ar = wm * 64 + f * 16 + l15;
    aof[f] = (ar >> 1) * 128 + (((ar & 1) * 4 + lhi) ^ ((ar >> 1) & 7)) * 16;
    int br = wn * 64 + f * 16 + l15;
    bof[f] = 16384 + (br >> 1) * 128 + (((br & 1) * 4 + lhi) ^ ((br >> 1) & 7)) * 16;
  }

  // ---- prologue: tile 0
  STAGE_A(0);
  LOAD_L(0);
  WRITE_B(0);      // compiler inserts vmcnt wait for L regs
  __syncthreads(); // drains A-DMA + B ds_writes

  for (int t = 0; t < KT; t++) {
    const char* pb = smc + (t & 1) * 8192;

    if (t + 1 < KT) LOAD_L(t + 1);       // issue early (8 VMEM, oldest)
#pragma unroll
    for (int f = 0; f < 4; f++) {
      a[f] = *reinterpret_cast<const bf16x8*>(pb + aof[f]);
      b[f] = *reinterpret_cast<const bf16x8*>(pb + bof[f]);
    }
    if (t + 1 < KT) STAGE_A(t + 1);      // DMA into opposite buf

#pragma unroll
    for (int mf = 0; mf < 4; mf++)
#pragma unroll
      for (int nf = 0; nf < 4; nf++)
        acc[mf][nf] = __builtin_amdgcn_mfma_f32_16x16x32_bf16(a[mf], b[nf], acc[mf][nf], 0, 0, 0);

    if (t + 1 < KT) WRITE_B(t + 1);      // opposite buf; waits L only (in-order)
    __syncthreads();                     // drain + barrier; next tile ready
  }
#undef STAGE_A
#undef LOAD_L
#undef WRITE_B

  // epilogue: D row = lhi*4+reg, col = l15 (verified C/D layout); bf16 out
#pragma unroll
  for (int mf = 0; mf < 4; mf++) {
#pragma unroll
    for (int nf = 0; nf < 4; nf++) {
#pragma unroll
      for (int rg = 0; rg < 4; rg++) {
        float v = acc[mf][nf][rg];
        int grow = mt * 128 + wm * 64 + mf * 16 + lhi * 4 + rg;
        int gcol = nt * 128 + wn * 64 + nf * 16 + l15;
        size_t off = ((size_t)e * CAP + grow) * NN + gcol;
        if constexpr (SILU) v = v / (1.0f + __expf(-v));  // silu
        Cout[off] = f2bf(v);
      }
    }
  }
}

// ------------------------------------------- weighted combine (no atomics)
// wave per token: lane reads uint4 (8 bf16) per slot row, writes 2 float4.
__global__ void k_combine(const u16* __restrict__ yws, const int* __restrict__ slot_pos,
                          const float* __restrict__ w, float* __restrict__ out) {
  int tk = blockIdx.x * 4 + (threadIdx.x >> 6);
  int lane = threadIdx.x & 63;
  int p0 = slot_pos[2 * tk], p1 = slot_pos[2 * tk + 1];
  float w0 = w[2 * tk], w1 = w[2 * tk + 1];
  uint4 ua = reinterpret_cast<const uint4*>(yws + (size_t)p0 * HID)[lane];
  uint4 ub = reinterpret_cast<const uint4*>(yws + (size_t)p1 * HID)[lane];
  float4 o0, o1;
  o0.x = w0 * bf2f(ua.x & 0xffffu) + w1 * bf2f(ub.x & 0xffffu);
  o0.y = w0 * bf2f(ua.x >> 16) + w1 * bf2f(ub.x >> 16);
  o0.z = w0 * bf2f(ua.y & 0xffffu) + w1 * bf2f(ub.y & 0xffffu);
  o0.w = w0 * bf2f(ua.y >> 16) + w1 * bf2f(ub.y >> 16);
  o1.x = w0 * bf2f(ua.z & 0xffffu) + w1 * bf2f(ub.z & 0xffffu);
  o1.y = w0 * bf2f(ua.z >> 16) + w1 * bf2f(ub.z >> 16);
  o1.z = w0 * bf2f(ua.w & 0xffffu) + w1 * bf2f(ub.w & 0xffffu);
  o1.w = w0 * bf2f(ua.w >> 16) + w1 * bf2f(ub.w >> 16);
  float4* dst = reinterpret_cast<float4*>(out + (size_t)tk * HID + lane * 8);
  dst[0] = o0;
  dst[1] = o1;
}

// ---------------------------------------------------------------- launcher
extern "C" void kernel_launch(void* const* d_in, const int* in_sizes, int n_in,
                              void* d_out, int out_size, void* d_ws, size_t ws_size,
                              hipStream_t stream) {
  const float* hs = (const float*)d_in[0];
  const float* wts = (const float*)d_in[1];
  const int* ids = (const int*)d_in[2];
  const float* W1 = (const float*)d_in[3];
  const float* W2 = (const float*)d_in[4];
  float* out = (float*)d_out;

  char* ws = (char*)d_ws;
  size_t o = 0;
  int* cnt = (int*)(ws + o);       o += 1024;
  int* slot_pos = (int*)(ws + o);  o += (size_t)NASSIGN * 4;
  int* tok_of = (int*)(ws + o);    o += (size_t)NASSIGN * 4;
  o = (o + 255) & ~(size_t)255;
  u16* Xg = (u16*)(ws + o);        o += (size_t)NASSIGN * HID * 2;      // 32 MB
  u16* hid = (u16*)(ws + o);       o += (size_t)NASSIGN * FFN * 2;      // 64 MB
  u16* yws = (u16*)(ws + o);       o += (size_t)NASSIGN * HID * 2;      // 32 MB

  hipMemsetAsync(cnt, 0, NEXP * sizeof(int), stream);
  k_route<<<(NASSIGN + 255) / 256, 256, 0, stream>>>(ids, cnt, tok_of, slot_pos);
  k_gather<<<NASSIGN / 4, 256, 0, stream>>>(hs, tok_of, Xg);
  k_gemm<HID, FFN, true><<<NEXP * (CAP / 128) * (FFN / 128), 256, 0, stream>>>(Xg, W1, hid);
  k_gemm<FFN, HID, false><<<NEXP * (CAP / 128) * (HID / 128), 256, 0, stream>>>(hid, W2, yws);
  k_combine<<<B_TOK / 4, 256, 0, stream>>>(yws, slot_pos, wts, out);
}